// Round 1
// baseline (207.853 us; speedup 1.0000x reference)
//
#include <hip/hip_runtime.h>

// ConfidenceProtoSegHead: sim = x(131072x256) . protosT(256x190), max over 10 protos,
// LayerNorm over 19 classes, write [b,19,h,w].
// Split-precision bf16 MFMA GEMM: x=xh+xl, p=ph+pl; sim ~= xh.ph + xh.pl + xl.ph.
//
// K1 prep: l2-normalize protos, pack bf16 hi/lo in MFMA B-fragment order (d_ws, 192KB).
// K2 gemm: 128-pix x 192-col tile/block, 4 waves x (2 mtiles x 12 ntiles),
//          K chunks of 32, double-buffered LDS (A 2x16KB + B 2x24KB = 80KB -> 2 blocks/CU),
//          epilogue max+LN through LDS reuse.

#define CC_   256
#define HW_   32768
#define NPIX_ 131072
#define NCLS_ 19
#define NPROT_ 10
#define NT_   12      // 192 padded proto columns
#define MBLK_ 128
#define NCHUNK_ 8     // 256 / 32
#define ABUF_  16384  // bytes per A buffer
#define BBUF_  24576  // bytes per B buffer

typedef __attribute__((ext_vector_type(8))) short bf16x8;
typedef __attribute__((ext_vector_type(4))) float f32x4;

__device__ __forceinline__ void gll16(const void* g, void* l) {
  __builtin_amdgcn_global_load_lds((__attribute__((address_space(1))) void*)(g),
                                   (__attribute__((address_space(3))) void*)(l), 16, 0, 0);
}

// ---------------- K1: normalize + pack prototypes --------------------------
// grid 192 blocks (19*10=190 real protos + 2 zero pads), 64 threads.
// B_packed layout: [cc(8)][j=nt*2+part(24)][lane(64)][16B]   (= 192 KB)
// Fragment semantics (nt, kstep=cc): lane L -> col = nt*16+(L&15) = proto idx,
// k-octet = L>>4: c = cc*32 + (L>>4)*8 + j.
__global__ void prep_protos(const float* __restrict__ protos, char* __restrict__ Bp) {
  const int p = blockIdx.x;     // proto column 0..191
  const int l = threadIdx.x;    // 0..63
  __shared__ float pn[256];
  float v[4] = {0.f, 0.f, 0.f, 0.f};
  float sq = 0.f;
  if (p < 190) {
    #pragma unroll
    for (int i = 0; i < 4; ++i) {
      v[i] = protos[p * 256 + l * 4 + i];
      sq += v[i] * v[i];
    }
  }
  #pragma unroll
  for (int off = 32; off > 0; off >>= 1) sq += __shfl_xor(sq, off, 64);
  const float scale = (p < 190) ? 1.0f / (sqrtf(sq) + 1e-12f) : 0.0f;
  #pragma unroll
  for (int i = 0; i < 4; ++i) pn[l * 4 + i] = v[i] * scale;
  __syncthreads();

  const int oct  = l >> 1;   // c-octet 0..31
  const int part = l & 1;    // 0=hi 1=lo
  bf16x8 o8;
  #pragma unroll
  for (int i = 0; i < 8; ++i) {
    const float f = pn[oct * 8 + i];
    const unsigned bits = __builtin_bit_cast(unsigned, f);
    if (part == 0) {
      o8[i] = (short)(bits >> 16);                       // truncated hi
    } else {
      const float hf = __builtin_bit_cast(float, bits & 0xFFFF0000u);
      const float lf = f - hf;
      o8[i] = (short)(__builtin_bit_cast(unsigned, lf) >> 16);
    }
  }
  const int cc = oct >> 2, oL = oct & 3;
  const int nt = p >> 4;
  const int j2 = nt * 2 + part;
  const int lane = (oL << 4) | (p & 15);
  *(bf16x8*)(Bp + (size_t)(((cc * 24 + j2) * 64 + lane) * 16)) = o8;
}

// ---------------- K2: fused GEMM + max + LayerNorm -------------------------
// LDS map: [0, 32768)            A bufs: buf*16384 + ((part*8+mt)*64 + L)*16
//          [32768, 81920)        B bufs: buf*24576 + ((nt*2+part)*64 + L)*16
//          epilogue reuse: sims 64 x 193 fp32 (49.4 KB)
__device__ __forceinline__ void convert_write(char* Adst, const float* xv,
                                              int chalf, int mt, int r15) {
  #pragma unroll
  for (int o2 = 0; o2 < 2; ++o2) {
    const int oct = chalf * 2 + o2;   // octet within chunk 0..3
    bf16x8 h, l;
    #pragma unroll
    for (int i = 0; i < 8; ++i) {
      const float f = xv[o2 * 8 + i];
      const unsigned bits = __builtin_bit_cast(unsigned, f);
      const float hf = __builtin_bit_cast(float, bits & 0xFFFF0000u);
      const float lf = f - hf;
      h[i] = (short)(bits >> 16);
      l[i] = (short)(__builtin_bit_cast(unsigned, lf) >> 16);
    }
    *(bf16x8*)(Adst + ((0 * 8 + mt) * 64 + (oct << 4) + r15) * 16) = h;
    *(bf16x8*)(Adst + ((1 * 8 + mt) * 64 + (oct << 4) + r15) * 16) = l;
  }
}

__launch_bounds__(256, 2)
__global__ void gemm_kernel(const float* __restrict__ x, const char* __restrict__ Bp,
                            const float* __restrict__ mw, const float* __restrict__ mb,
                            float* __restrict__ out) {
  __shared__ __align__(16) char smem[81920];
  char* Abase = smem;
  char* Bbase = smem + 32768;

  const int tid  = threadIdx.x;
  const int wave = tid >> 6;
  const int lane = tid & 63;
  const int n0   = blockIdx.x * MBLK_;
  const int b    = n0 >> 15;           // batch (blocks never straddle: 32768 % 128 == 0)
  const int hw0  = n0 & (HW_ - 1);
  const float* xb = x + (size_t)b * CC_ * HW_ + hw0;

  const int pixl  = tid & 127;   // staging pixel
  const int chalf = tid >> 7;    // staging c half (16 c each)
  const int mt_s  = pixl >> 4;
  const int r15   = pixl & 15;

  f32x4 acc[2][NT_];
  #pragma unroll
  for (int m = 0; m < 2; ++m)
    #pragma unroll
    for (int nt = 0; nt < NT_; ++nt) acc[m][nt] = (f32x4){0.f, 0.f, 0.f, 0.f};

  float xv[16];
  // ---- prologue: stage chunk 0
  {
    const int c0 = chalf * 16;
    #pragma unroll
    for (int j = 0; j < 16; ++j) xv[j] = xb[(size_t)(c0 + j) * HW_ + pixl];
    #pragma unroll
    for (int i = 0; i < 6; ++i) {
      const int j2 = wave + 4 * i;
      gll16(Bp + (size_t)((j2 * 64 + lane) * 16), Bbase + j2 * 1024 + lane * 16);
    }
    convert_write(Abase, xv, chalf, mt_s, r15);
  }
  __syncthreads();

  int buf = 0;
  for (int cc = 0; cc < NCHUNK_; ++cc) {
    const int nb = buf ^ 1;
    if (cc + 1 < NCHUNK_) {
      // issue next-chunk A loads (regs) + B global_load_lds early; write late (T14)
      const int c0 = (cc + 1) * 32 + chalf * 16;
      #pragma unroll
      for (int j = 0; j < 16; ++j) xv[j] = xb[(size_t)(c0 + j) * HW_ + pixl];
      #pragma unroll
      for (int i = 0; i < 6; ++i) {
        const int j2 = wave + 4 * i;
        gll16(Bp + (size_t)((((cc + 1) * 24 + j2) * 64 + lane) * 16),
              Bbase + nb * BBUF_ + j2 * 1024 + lane * 16);
      }
    }
    // ---- compute chunk cc
    const char* A  = Abase + buf * ABUF_;
    const char* Bq = Bbase + buf * BBUF_;
    bf16x8 ahi[2], alo[2];
    #pragma unroll
    for (int m = 0; m < 2; ++m) {
      const int mt = wave * 2 + m;
      ahi[m] = *(const bf16x8*)(A + ((0 * 8 + mt) * 64 + lane) * 16);
      alo[m] = *(const bf16x8*)(A + ((1 * 8 + mt) * 64 + lane) * 16);
    }
    #pragma unroll
    for (int nt = 0; nt < NT_; ++nt) {
      const bf16x8 bhi = *(const bf16x8*)(Bq + ((nt * 2 + 0) * 64 + lane) * 16);
      const bf16x8 blo = *(const bf16x8*)(Bq + ((nt * 2 + 1) * 64 + lane) * 16);
      #pragma unroll
      for (int m = 0; m < 2; ++m) {
        acc[m][nt] = __builtin_amdgcn_mfma_f32_16x16x32_bf16(ahi[m], bhi, acc[m][nt], 0, 0, 0);
        acc[m][nt] = __builtin_amdgcn_mfma_f32_16x16x32_bf16(alo[m], bhi, acc[m][nt], 0, 0, 0);
        acc[m][nt] = __builtin_amdgcn_mfma_f32_16x16x32_bf16(ahi[m], blo, acc[m][nt], 0, 0, 0);
      }
    }
    if (cc + 1 < NCHUNK_) convert_write(Abase + nb * ABUF_, xv, chalf, mt_s, r15);
    __syncthreads();
    buf = nb;
  }

  // ---- epilogue: max over 10 protos, LayerNorm over 19 classes
  float* sims = (float*)smem;   // [64][193]
  for (int bat = 0; bat < 2; ++bat) {
    if ((wave >> 1) == bat) {
      const int wl = wave & 1;
      #pragma unroll
      for (int m = 0; m < 2; ++m) {
        const int pixbase = (wl * 2 + m) * 16 + (lane >> 4) * 4;  // row within batch
        #pragma unroll
        for (int nt = 0; nt < NT_; ++nt) {
          const int col = nt * 16 + (lane & 15);
          #pragma unroll
          for (int r = 0; r < 4; ++r)
            sims[(pixbase + r) * 193 + col] = acc[m][nt][r];
        }
      }
    }
    __syncthreads();
    if (tid < 64) {
      const int pl = bat * 64 + tid;    // pixel within block
      float mx[NCLS_];
      #pragma unroll
      for (int k = 0; k < NCLS_; ++k) {
        float vmax = sims[tid * 193 + k * 10];
        #pragma unroll
        for (int m2 = 1; m2 < 10; ++m2)
          vmax = fmaxf(vmax, sims[tid * 193 + k * 10 + m2]);
        mx[k] = vmax;
      }
      float mu = 0.f;
      #pragma unroll
      for (int k = 0; k < NCLS_; ++k) mu += mx[k];
      mu *= (1.0f / NCLS_);
      float var = 0.f;
      #pragma unroll
      for (int k = 0; k < NCLS_; ++k) { const float d = mx[k] - mu; var += d * d; }
      var *= (1.0f / NCLS_);
      const float rstd = rsqrtf(var + 1e-5f);
      const int hw = hw0 + pl;
      #pragma unroll
      for (int k = 0; k < NCLS_; ++k) {
        out[((size_t)(b * NCLS_ + k) << 15) + hw] = (mx[k] - mu) * rstd * mw[k] + mb[k];
      }
    }
    __syncthreads();
  }
}

extern "C" void kernel_launch(void* const* d_in, const int* in_sizes, int n_in,
                              void* d_out, int out_size, void* d_ws, size_t ws_size,
                              hipStream_t stream) {
  const float* x      = (const float*)d_in[0];
  const float* protos = (const float*)d_in[1];
  const float* mw     = (const float*)d_in[2];
  const float* mb     = (const float*)d_in[3];
  float* out = (float*)d_out;
  char* Bp   = (char*)d_ws;   // 192 KB packed prototypes

  prep_protos<<<192, 64, 0, stream>>>(protos, Bp);
  gemm_kernel<<<NPIX_ / MBLK_, 256, 0, stream>>>(x, Bp, mw, mb, out);
}